// Round 2
// baseline (871.350 us; speedup 1.0000x reference)
//
#include <hip/hip_runtime.h>

// LaplacianLoss: out[b] = sum_{n,d} ( sum_m L[n,m] * x[b,m,d] )^2
// x: (4, 10242, 3) fp32; L: (10242, 10242) fp32; out: 4 fp32.
//
// HBM-bound on streaming L (419.6 MB, floor ~67 us @6.3 TB/s).
// Round-2 design: no LDS, no barriers. Each wave owns 5 rows; each lane
// owns 4 consecutive m per iteration (float4 L loads, coalesced 1 KB/instr).
// Explicit register ping-pong prefetch of next iteration's L keeps
// ~5 KB/lane-group in flight per wave -> s_waitcnt vmcnt(N>0), never a
// full drain. x read per-iteration from L2/L3 (492 KB resident).
// Per-wave partials (reduce-before-square) -> d_ws -> tiny reduce kernel.

#define NV    10242
#define NB    4
#define RPW   5                       // rows per wave
#define WPB   4                       // waves per block
#define RPB   (RPW * WPB)             // 20 rows per block
#define NBLK  ((NV + RPB - 1) / RPB)  // 513 blocks
#define NITER 40                      // 40 * 256 = 10240 m's in main loop
#define NPART (NBLK * WPB)            // wave-partial groups (each NB floats)

typedef float float4u __attribute__((ext_vector_type(4), aligned(4)));

__global__ __launch_bounds__(256, 3) void lap_main(
    const float* __restrict__ x,
    const float* __restrict__ L,
    float* __restrict__ part)
{
    const int tid  = threadIdx.x;
    const int wave = tid >> 6;
    const int lane = tid & 63;
    const int g    = blockIdx.x;
    const int row0 = g * RPB + wave * RPW;

    float* mypart = part + (size_t)(g * WPB + wave) * NB;

    int nvalid = NV - row0;
    if (nvalid > RPW) nvalid = RPW;
    if (nvalid <= 0) {                 // wave-uniform; last block's idle waves
        if (lane == 0)
            for (int b = 0; b < NB; ++b) mypart[b] = 0.f;
        return;
    }

    // Clamped row pointers; invalid rows masked in epilogue.
    const float* Lrow[RPW];
#pragma unroll
    for (int r = 0; r < RPW; ++r) {
        int n = row0 + r;
        if (n > NV - 1) n = NV - 1;
        Lrow[r] = L + (size_t)n * NV;
    }

    float acc[RPW][12];
#pragma unroll
    for (int r = 0; r < RPW; ++r)
#pragma unroll
        for (int k = 0; k < 12; ++k) acc[r][k] = 0.f;

    const int lane4 = lane * 4;

    auto loadL = [&](float4u (&Lb)[RPW], int it) {
        const int m = it * 256 + lane4;
#pragma unroll
        for (int r = 0; r < RPW; ++r)
            Lb[r] = *(const float4u*)(Lrow[r] + m);
    };

    auto compute = [&](const float4u (&Lb)[RPW], int it) {
        const int m = it * 256 + lane4;
#pragma unroll
        for (int b = 0; b < NB; ++b) {
            // 12 contiguous floats: x[b, m..m+3, 0..2]
            const float* xp = x + ((size_t)b * NV + m) * 3;
            float4u x0 = *(const float4u*)(xp);
            float4u x1 = *(const float4u*)(xp + 4);
            float4u x2 = *(const float4u*)(xp + 8);
            float xv[12] = {x0.x, x0.y, x0.z, x0.w,
                            x1.x, x1.y, x1.z, x1.w,
                            x2.x, x2.y, x2.z, x2.w};
            // xv[mi*3 + d]
#pragma unroll
            for (int r = 0; r < RPW; ++r) {
                float4u l4 = Lb[r];
#pragma unroll
                for (int d = 0; d < 3; ++d) {
                    acc[r][b * 3 + d] += l4.x * xv[0 + d]
                                       + l4.y * xv[3 + d]
                                       + l4.z * xv[6 + d]
                                       + l4.w * xv[9 + d];
                }
            }
        }
    };

    float4u A[RPW], Bb[RPW];
    loadL(A, 0);
#pragma unroll 1
    for (int it = 0; it < NITER; it += 2) {
        loadL(Bb, it + 1);                              // prefetch it+1
        compute(A, it);
        loadL(A, (it + 2 < NITER) ? (it + 2) : 0);      // prefetch it+2 (dummy on last)
        compute(Bb, it + 1);
    }

    // Tail m = 10240, 10241 (lanes 0,1 only).
    if (lane < 2) {
        const int m = NITER * 256 + lane;
#pragma unroll
        for (int r = 0; r < RPW; ++r) {
            float lv = Lrow[r][m];
#pragma unroll
            for (int b = 0; b < NB; ++b)
#pragma unroll
                for (int d = 0; d < 3; ++d)
                    acc[r][b * 3 + d] += lv * x[((size_t)b * NV + m) * 3 + d];
        }
    }

    // Reduce each dot product across the 64 lanes (before squaring).
#pragma unroll
    for (int r = 0; r < RPW; ++r)
#pragma unroll
        for (int k = 0; k < 12; ++k) {
            float v = acc[r][k];
            for (int off = 32; off > 0; off >>= 1)
                v += __shfl_down(v, off, 64);
            acc[r][k] = v;
        }

    if (lane == 0) {
#pragma unroll
        for (int b = 0; b < NB; ++b) {
            float s = 0.f;
            for (int r = 0; r < nvalid; ++r) {
                float v0 = acc[r][b * 3 + 0];
                float v1 = acc[r][b * 3 + 1];
                float v2 = acc[r][b * 3 + 2];
                s += v0 * v0 + v1 * v1 + v2 * v2;
            }
            mypart[b] = s;
        }
    }
}

__global__ void lap_reduce(const float* __restrict__ part,
                           float* __restrict__ out)
{
    __shared__ float sdata[256];
    const int tid = threadIdx.x;
    const int b = tid & 3;
    float s = 0.f;
    for (int i = tid >> 2; i < NPART; i += 64)
        s += part[(size_t)i * NB + b];
    sdata[tid] = s;
    __syncthreads();
    if (tid < 4) {
        float t = 0.f;
        for (int i = tid; i < 256; i += 4) t += sdata[i];
        out[tid] = t;   // tid == b for tid < 4
    }
}

extern "C" void kernel_launch(void* const* d_in, const int* in_sizes, int n_in,
                              void* d_out, int out_size, void* d_ws, size_t ws_size,
                              hipStream_t stream)
{
    const float* x = (const float*)d_in[0];   // (4, 10242, 3)
    const float* L = (const float*)d_in[1];   // (10242, 10242)
    float* out  = (float*)d_out;              // (4,)
    float* part = (float*)d_ws;               // NPART * NB floats (~33 KB)

    lap_main<<<NBLK, 256, 0, stream>>>(x, L, part);
    lap_reduce<<<1, 256, 0, stream>>>(part, out);
}

// Round 3
// 610.493 us; speedup vs baseline: 1.4273x; 1.4273x over previous
//
#include <hip/hip_runtime.h>

// LaplacianLoss: out[b] = sum_{n,d} ( sum_m L[n,m] * x[b,m,d] )^2
// x: (4, 10242, 3) fp32; L: (10242, 10242) fp32; out: 4 fp32.
//
// Round 3: k-split streaming GEMV. Grid (641 row-groups x 4 k-chunks),
// 4 waves/block, 4 rows/wave. L streamed as float2 pairs (odd rows are only
// 8B-aligned), register ping-pong prefetch with x-before-L issue order so
// waiting on x leaves the L prefetch in flight (vmcnt>0). x pre-interleaved
// into xI[chunk][12][4] (one 192B contiguous slab per lane per iter, L2-hot).
// Partial dots (pre-square) written once per (kc,row,k) into yp — no atomics,
// deterministic. Two small reduce kernels finish sum(lx*lx) per batch.
//
// NO private arrays with non-constant indexing (round-2 scratch-spill lesson).

#define NV     10242
#define NB     4
#define KS     4                      // k-split factor
#define RPW    4                      // rows per wave
#define WPB    4                      // waves per block
#define RPB    (RPW*WPB)              // 16 rows per block
#define NRG    ((NV + RPB - 1)/RPB)   // 641 row groups
#define CHUNKS 2560                   // float4 m-chunks (m < 10240)
#define CPK    (CHUNKS/KS)            // 640 chunks per k-range
#define ITERS  (CPK/64)               // 10 iterations per wave
#define R1B    40                     // reduce-1 blocks

typedef float f2v __attribute__((ext_vector_type(2)));
typedef float f4v __attribute__((ext_vector_type(4)));

// d_ws float layout
#define XI_OFF 0
#define XI_SZ  (CHUNKS*48)            // 122880 floats
#define YP_OFF XI_SZ
#define KSTR   (NV*12)                // 122904 floats per k-chunk plane
#define YP_SZ  (KS*KSTR)
#define P_OFF  (YP_OFF + YP_SZ)

// ---- pass 0: interleave x -> xI[c][k][j], k = b*3+d, m = 4c+j ----
__global__ __launch_bounds__(256) void build_xI(const float* __restrict__ x,
                                                float* __restrict__ xI)
{
    int g = blockIdx.x * 256 + threadIdx.x;      // [0, 30720)
    if (g >= CHUNKS * 12) return;
    int c = g / 12;
    int k = g - c * 12;
    int b = k / 3;
    int d = k - b * 3;
    const float* xp = x + ((size_t)b * NV + 4 * c) * 3 + d;
    f4v v;
    v.x = xp[0]; v.y = xp[3]; v.z = xp[6]; v.w = xp[9];
    ((f4v*)xI)[g] = v;                           // flat f4 index c*12+k == g
}

// ---- main: stream L, accumulate partial dots per k-chunk ----
#define LOADL(p, off)                                         \
    p##0lo = *(const f2v*)(Lp0 + (off));                      \
    p##0hi = *(const f2v*)(Lp0 + (off) + 2);                  \
    p##1lo = *(const f2v*)(Lp1 + (off));                      \
    p##1hi = *(const f2v*)(Lp1 + (off) + 2);                  \
    p##2lo = *(const f2v*)(Lp2 + (off));                      \
    p##2hi = *(const f2v*)(Lp2 + (off) + 2);                  \
    p##3lo = *(const f2v*)(Lp3 + (off));                      \
    p##3hi = *(const f2v*)(Lp3 + (off) + 2);

#define FMA_ROW(r, p)                                                        \
    acc[r][0]  += p##r##lo.x*xv0.x + p##r##lo.y*xv0.y + p##r##hi.x*xv0.z + p##r##hi.y*xv0.w;   \
    acc[r][1]  += p##r##lo.x*xv1.x + p##r##lo.y*xv1.y + p##r##hi.x*xv1.z + p##r##hi.y*xv1.w;   \
    acc[r][2]  += p##r##lo.x*xv2.x + p##r##lo.y*xv2.y + p##r##hi.x*xv2.z + p##r##hi.y*xv2.w;   \
    acc[r][3]  += p##r##lo.x*xv3.x + p##r##lo.y*xv3.y + p##r##hi.x*xv3.z + p##r##hi.y*xv3.w;   \
    acc[r][4]  += p##r##lo.x*xv4.x + p##r##lo.y*xv4.y + p##r##hi.x*xv4.z + p##r##hi.y*xv4.w;   \
    acc[r][5]  += p##r##lo.x*xv5.x + p##r##lo.y*xv5.y + p##r##hi.x*xv5.z + p##r##hi.y*xv5.w;   \
    acc[r][6]  += p##r##lo.x*xv6.x + p##r##lo.y*xv6.y + p##r##hi.x*xv6.z + p##r##hi.y*xv6.w;   \
    acc[r][7]  += p##r##lo.x*xv7.x + p##r##lo.y*xv7.y + p##r##hi.x*xv7.z + p##r##hi.y*xv7.w;   \
    acc[r][8]  += p##r##lo.x*xv8.x + p##r##lo.y*xv8.y + p##r##hi.x*xv8.z + p##r##hi.y*xv8.w;   \
    acc[r][9]  += p##r##lo.x*xv9.x + p##r##lo.y*xv9.y + p##r##hi.x*xv9.z + p##r##hi.y*xv9.w;   \
    acc[r][10] += p##r##lo.x*xv10.x + p##r##lo.y*xv10.y + p##r##hi.x*xv10.z + p##r##hi.y*xv10.w; \
    acc[r][11] += p##r##lo.x*xv11.x + p##r##lo.y*xv11.y + p##r##hi.x*xv11.z + p##r##hi.y*xv11.w;

// One half-iteration: issue 12 x loads, then prefetch next L into `nxt`,
// then FMA on `cur`. x issued before L so the x-wait keeps L in flight.
#define HALF(cur, nxt, nxtoff)                                \
    {                                                         \
        f4v xv0  = xp[0],  xv1  = xp[1],  xv2  = xp[2];       \
        f4v xv3  = xp[3],  xv4  = xp[4],  xv5  = xp[5];       \
        f4v xv6  = xp[6],  xv7  = xp[7],  xv8  = xp[8];       \
        f4v xv9  = xp[9],  xv10 = xp[10], xv11 = xp[11];      \
        LOADL(nxt, nxtoff);                                   \
        FMA_ROW(0, cur)                                       \
        FMA_ROW(1, cur)                                       \
        FMA_ROW(2, cur)                                       \
        FMA_ROW(3, cur)                                       \
        xp += 12 * 64;                                        \
    }

__global__ __launch_bounds__(256) void lap_main(
    const float* __restrict__ x,
    const float* __restrict__ L,
    const float* __restrict__ xI,
    float* __restrict__ yp)
{
    const int tid  = threadIdx.x;
    const int wave = tid >> 6;
    const int lane = tid & 63;
    const int rg   = blockIdx.x;
    const int kc   = blockIdx.y;
    const int row0 = rg * RPB + wave * RPW;
    const int nvalid = (NV - row0 < RPW) ? (NV - row0) : RPW;
    if (nvalid <= 0) return;     // wave-uniform, no barriers in kernel

    const int r0 = row0;
    const int r1 = (row0 + 1 < NV) ? row0 + 1 : NV - 1;
    const int r2 = (row0 + 2 < NV) ? row0 + 2 : NV - 1;
    const int r3 = (row0 + 3 < NV) ? row0 + 3 : NV - 1;

    const int mbase = kc * (CPK * 4) + lane * 4;   // starting m for this lane
    const float* Lp0 = L + (size_t)r0 * NV + mbase;
    const float* Lp1 = L + (size_t)r1 * NV + mbase;
    const float* Lp2 = L + (size_t)r2 * NV + mbase;
    const float* Lp3 = L + (size_t)r3 * NV + mbase;

    const f4v* xp = (const f4v*)xI + ((size_t)kc * CPK + lane) * 12;

    float acc[RPW][12];
#pragma unroll
    for (int r = 0; r < RPW; ++r)
#pragma unroll
        for (int k = 0; k < 12; ++k) acc[r][k] = 0.f;

    f2v a0lo, a0hi, a1lo, a1hi, a2lo, a2hi, a3lo, a3hi;
    f2v b0lo, b0hi, b1lo, b1hi, b2lo, b2hi, b3lo, b3hi;

    LOADL(a, 0);                         // preload iteration 0
#pragma unroll 1
    for (int it = 0; it < ITERS; it += 2) {
        const int offA = (it + 1) * 256;                         // prefetch it+1 (always valid)
        const int offB = (it + 2 < ITERS) ? (it + 2) * 256 : 0;  // dummy re-read on last trip
        HALF(a, b, offA)
        HALF(b, a, offB)
    }

    // tail m = 10240, 10241 (only for the last k-chunk; lanes 0,1)
    if (kc == KS - 1 && lane < 2) {
        const int m = 10240 + lane;
        const float l0 = L[(size_t)r0 * NV + m];
        const float l1 = L[(size_t)r1 * NV + m];
        const float l2 = L[(size_t)r2 * NV + m];
        const float l3 = L[(size_t)r3 * NV + m];
#pragma unroll
        for (int k = 0; k < 12; ++k) {
            const int b = k / 3, d = k - 3 * (k / 3);
            const float xv = x[((size_t)b * NV + m) * 3 + d];
            acc[0][k] += l0 * xv;
            acc[1][k] += l1 * xv;
            acc[2][k] += l2 * xv;
            acc[3][k] += l3 * xv;
        }
    }

    // reduce each partial dot across the 64 lanes (BEFORE squaring)
#pragma unroll
    for (int r = 0; r < RPW; ++r)
#pragma unroll
        for (int k = 0; k < 12; ++k) {
            float v = acc[r][k];
            for (int off = 32; off > 0; off >>= 1)
                v += __shfl_down(v, off, 64);
            acc[r][k] = v;
        }

    if (lane == 0) {
        float* dst = yp + (size_t)kc * KSTR + (size_t)row0 * 12;
#pragma unroll
        for (int r = 0; r < RPW; ++r) {
            if (r < nvalid) {
#pragma unroll
                for (int k = 0; k < 12; ++k) dst[r * 12 + k] = acc[r][k];
            }
        }
    }
}

// ---- reduce 1: combine k-chunks, square, per-block batch partials ----
__global__ __launch_bounds__(256) void lap_r1(const float* __restrict__ yp,
                                              float* __restrict__ part)
{
    __shared__ float sdata[WPB][NB];
    float s0 = 0.f, s1 = 0.f, s2 = 0.f, s3 = 0.f;
    for (int n = blockIdx.x * 256 + threadIdx.x; n < NV; n += R1B * 256) {
        const float* p = yp + (size_t)n * 12;
#pragma unroll
        for (int k = 0; k < 12; ++k) {
            float v = p[k] + p[KSTR + k] + p[2 * KSTR + k] + p[3 * KSTR + k];
            float vv = v * v;
            if (k < 3)       s0 += vv;
            else if (k < 6)  s1 += vv;
            else if (k < 9)  s2 += vv;
            else             s3 += vv;
        }
    }
    for (int off = 32; off > 0; off >>= 1) {
        s0 += __shfl_down(s0, off, 64);
        s1 += __shfl_down(s1, off, 64);
        s2 += __shfl_down(s2, off, 64);
        s3 += __shfl_down(s3, off, 64);
    }
    const int wave = threadIdx.x >> 6, lane = threadIdx.x & 63;
    if (lane == 0) {
        sdata[wave][0] = s0; sdata[wave][1] = s1;
        sdata[wave][2] = s2; sdata[wave][3] = s3;
    }
    __syncthreads();
    if (threadIdx.x < NB) {
        part[blockIdx.x * NB + threadIdx.x] =
            sdata[0][threadIdx.x] + sdata[1][threadIdx.x] +
            sdata[2][threadIdx.x] + sdata[3][threadIdx.x];
    }
}

// ---- reduce 2: final 40x4 -> 4 ----
__global__ void lap_r2(const float* __restrict__ part, float* __restrict__ out)
{
    const int tid = threadIdx.x;
    if (tid < NB) {
        float s = 0.f;
        for (int i = 0; i < R1B; ++i) s += part[i * NB + tid];
        out[tid] = s;
    }
}

extern "C" void kernel_launch(void* const* d_in, const int* in_sizes, int n_in,
                              void* d_out, int out_size, void* d_ws, size_t ws_size,
                              hipStream_t stream)
{
    const float* x = (const float*)d_in[0];   // (4, 10242, 3)
    const float* L = (const float*)d_in[1];   // (10242, 10242)
    float* out = (float*)d_out;               // (4,)
    float* ws  = (float*)d_ws;                // >= 2.5 MB

    float* xI   = ws + XI_OFF;
    float* yp   = ws + YP_OFF;
    float* part = ws + P_OFF;

    build_xI<<<(CHUNKS * 12 + 255) / 256, 256, 0, stream>>>(x, xI);
    lap_main<<<dim3(NRG, KS), 256, 0, stream>>>(x, L, xI, yp);
    lap_r1<<<R1B, 256, 0, stream>>>(yp, part);
    lap_r2<<<1, 64, 0, stream>>>(part, out);
}